// Round 1
// baseline (1597.600 us; speedup 1.0000x reference)
//
#include <hip/hip_runtime.h>
#include <math.h>

#define NSL 0.2f   // leaky relu negative slope
#define IN_DIM 165
#define HID 128
#define OUT_H 64

// ---------- degree / norm ----------
__global__ __launch_bounds__(256) void deg_kernel(const int* __restrict__ col, int E,
                                                  float* __restrict__ deg) {
    int e = blockIdx.x * 256 + threadIdx.x;
    if (e < E) atomicAdd(&deg[col[e]], 1.0f);
}

__global__ __launch_bounds__(256) void dinv_kernel(const float* __restrict__ deg,
                                                   float* __restrict__ dinv, int n) {
    int i = blockIdx.x * 256 + threadIdx.x;
    if (i < n) dinv[i] = rsqrtf(deg[i] + 1.0f);   // +1 = self loop
}

// ---------- generic tiled fp32 GEMM: C[M,N] = A[M,K] @ B[K,N] ----------
template<int BM, int BN, int BK, int TM, int TN>
__global__ __launch_bounds__(256) void gemm_kernel(const float* __restrict__ A,
                                                   const float* __restrict__ B,
                                                   float* __restrict__ C,
                                                   int M, int K, int N) {
    __shared__ float As[BM][BK + 1];
    __shared__ float Bs[BK][BN];
    const int t = threadIdx.x;
    const int tx = t % (BN / TN);
    const int ty = t / (BN / TN);
    const int row0 = blockIdx.y * BM;
    const int col0 = blockIdx.x * BN;

    float acc[TM][TN];
#pragma unroll
    for (int r = 0; r < TM; r++)
#pragma unroll
        for (int c = 0; c < TN; c++) acc[r][c] = 0.f;

    for (int k0 = 0; k0 < K; k0 += BK) {
        for (int i = t; i < BM * BK; i += 256) {
            int r = i / BK, c = i % BK;
            int gr = row0 + r, gc = k0 + c;
            As[r][c] = (gr < M && gc < K) ? A[(size_t)gr * K + gc] : 0.f;
        }
        for (int i = t; i < BK * BN; i += 256) {
            int r = i / BN, c = i % BN;
            int gr = k0 + r;
            Bs[r][c] = (gr < K) ? B[(size_t)gr * N + col0 + c] : 0.f;
        }
        __syncthreads();
#pragma unroll
        for (int kk = 0; kk < BK; kk++) {
            float a[TM], b[TN];
#pragma unroll
            for (int r = 0; r < TM; r++) a[r] = As[ty * TM + r][kk];
#pragma unroll
            for (int c = 0; c < TN; c++) b[c] = Bs[kk][tx * TN + c];
#pragma unroll
            for (int r = 0; r < TM; r++)
#pragma unroll
                for (int c = 0; c < TN; c++) acc[r][c] += a[r] * b[c];
        }
        __syncthreads();
    }
#pragma unroll
    for (int r = 0; r < TM; r++) {
        int gr = row0 + ty * TM + r;
        if (gr < M) {
#pragma unroll
            for (int c = 0; c < TN; c++)
                C[(size_t)gr * N + col0 + tx * TN + c] = acc[r][c];
        }
    }
}

// ---------- GCN edge scatter: g[col] += h1[row] * dinv[row]*dinv[col] ----------
__global__ __launch_bounds__(256) void gcn_scatter(const int* __restrict__ rowi,
                                                   const int* __restrict__ coli, int E,
                                                   const float* __restrict__ h1,
                                                   const float* __restrict__ dinv,
                                                   float* __restrict__ g) {
    int w = (blockIdx.x * 256 + threadIdx.x) >> 6;
    int lane = threadIdx.x & 63;
    if (w >= E) return;
    int r = rowi[w], c = coli[w];
    float norm = dinv[r] * dinv[c];
    float v0 = h1[(size_t)r * HID + lane] * norm;
    float v1 = h1[(size_t)r * HID + lane + 64] * norm;
    atomicAdd(&g[(size_t)c * HID + lane], v0);
    atomicAdd(&g[(size_t)c * HID + lane + 64], v1);
}

// ---------- GCN epilogue: self loop + bias + relu (in place on g) ----------
__global__ __launch_bounds__(256) void gcn_finish(const float* __restrict__ h1,
                                                  const float* __restrict__ dinv,
                                                  const float* __restrict__ b1,
                                                  float* __restrict__ g, int n) {
    size_t idx = (size_t)blockIdx.x * 256 + threadIdx.x;
    if (idx >= (size_t)n * HID) return;
    int i = idx / HID, f = idx % HID;
    float d = dinv[i];
    float v = g[idx] + h1[idx] * d * d + b1[f];
    g[idx] = fmaxf(v, 0.f);
}

// ---------- per-node attention coefficients ----------
__global__ __launch_bounds__(256) void attn_coef(const float* __restrict__ h2,
                                                 const float* __restrict__ a_src,
                                                 const float* __restrict__ a_dst,
                                                 float* __restrict__ es,
                                                 float* __restrict__ ed, int n) {
    int i = blockIdx.x * 4 + (threadIdx.x >> 6);
    int lane = threadIdx.x & 63;
    if (i >= n) return;
    float h = h2[(size_t)i * OUT_H + lane];
    float vs = h * a_src[lane];
    float vd = h * a_dst[lane];
    for (int off = 32; off; off >>= 1) {
        vs += __shfl_down(vs, off);
        vd += __shfl_down(vd, off);
    }
    if (lane == 0) { es[i] = vs; ed[i] = vd; }
}

// ---------- monotone float<->uint key for atomicMax ----------
__device__ inline unsigned fkey(float x) {
    unsigned b = __float_as_uint(x);
    return (b & 0x80000000u) ? ~b : (b | 0x80000000u);
}
__device__ inline float funkey(unsigned k) {
    unsigned b = (k & 0x80000000u) ? (k & 0x7FFFFFFFu) : ~k;
    return __uint_as_float(b);
}

__global__ __launch_bounds__(256) void gat_max(const int* __restrict__ rowi,
                                               const int* __restrict__ coli, int E,
                                               const float* __restrict__ es,
                                               const float* __restrict__ ed,
                                               unsigned* __restrict__ mkey) {
    int e = blockIdx.x * 256 + threadIdx.x;
    if (e >= E) return;
    float v = es[rowi[e]] + ed[coli[e]];
    v = v > 0.f ? v : NSL * v;
    atomicMax(&mkey[coli[e]], fkey(v));
}

// ---------- self-loop init: m, s=exp(e_self-m), acc = exs*h2[i] ----------
__global__ __launch_bounds__(256) void gat_selfinit(const float* __restrict__ h2,
                                                    const float* __restrict__ es,
                                                    const float* __restrict__ ed,
                                                    const unsigned* __restrict__ mkey,
                                                    float* __restrict__ mfloat,
                                                    float* __restrict__ s,
                                                    float* __restrict__ acc, int n) {
    int i = blockIdx.x * 4 + (threadIdx.x >> 6);
    int lane = threadIdx.x & 63;
    if (i >= n) return;
    float eself = es[i] + ed[i];
    eself = eself > 0.f ? eself : NSL * eself;
    unsigned k = mkey[i];
    float m = (k == 0u) ? eself : fmaxf(funkey(k), eself);
    float exs = expf(eself - m);
    if (lane == 0) { mfloat[i] = m; s[i] = exs; }
    acc[(size_t)i * OUT_H + lane] = exs * h2[(size_t)i * OUT_H + lane];
}

// ---------- GAT edge scatter: s[col]+=ex ; acc[col] += ex * h2[row] ----------
__global__ __launch_bounds__(256) void gat_scatter(const int* __restrict__ rowi,
                                                   const int* __restrict__ coli, int E,
                                                   const float* __restrict__ es,
                                                   const float* __restrict__ ed,
                                                   const float* __restrict__ mfloat,
                                                   const float* __restrict__ h2,
                                                   float* __restrict__ s,
                                                   float* __restrict__ acc) {
    int w = (blockIdx.x * 256 + threadIdx.x) >> 6;
    int lane = threadIdx.x & 63;
    if (w >= E) return;
    int r = rowi[w], c = coli[w];
    float v = es[r] + ed[c];
    v = v > 0.f ? v : NSL * v;
    float ex = expf(v - mfloat[c]);
    if (lane == 0) atomicAdd(&s[c], ex);
    atomicAdd(&acc[(size_t)c * OUT_H + lane],
              ex * h2[(size_t)r * OUT_H + lane]);
}

// ---------- epilogue: relu(acc/s + bg) @ Wfc + bfc ----------
__global__ __launch_bounds__(256) void gat_finish(const float* __restrict__ acc,
                                                  const float* __restrict__ s,
                                                  const float* __restrict__ bg,
                                                  const float* __restrict__ Wfc,
                                                  const float* __restrict__ bfc,
                                                  float* __restrict__ out, int n) {
    int i = blockIdx.x * 4 + (threadIdx.x >> 6);
    int lane = threadIdx.x & 63;
    if (i >= n) return;
    float o = fmaxf(acc[(size_t)i * OUT_H + lane] / s[i] + bg[lane], 0.f);
    float p0 = o * Wfc[lane * 2 + 0];
    float p1 = o * Wfc[lane * 2 + 1];
    for (int off = 32; off; off >>= 1) {
        p0 += __shfl_down(p0, off);
        p1 += __shfl_down(p1, off);
    }
    if (lane == 0) {
        out[(size_t)i * 2 + 0] = p0 + bfc[0];
        out[(size_t)i * 2 + 1] = p1 + bfc[1];
    }
}

extern "C" void kernel_launch(void* const* d_in, const int* in_sizes, int n_in,
                              void* d_out, int out_size, void* d_ws, size_t ws_size,
                              hipStream_t stream) {
    const float* x     = (const float*)d_in[0];
    const int*   ei    = (const int*)d_in[1];
    const float* W1    = (const float*)d_in[2];
    const float* b1    = (const float*)d_in[3];
    const float* Wg    = (const float*)d_in[4];
    const float* a_src = (const float*)d_in[5];
    const float* a_dst = (const float*)d_in[6];
    const float* bg    = (const float*)d_in[7];
    const float* Wfc   = (const float*)d_in[8];
    const float* bfc   = (const float*)d_in[9];
    float* out = (float*)d_out;

    const int N = in_sizes[0] / IN_DIM;
    const int E = in_sizes[1] / 2;
    const int* rowi = ei;
    const int* coli = ei + E;

    // workspace layout (floats), with aliasing:
    //   bufA: N      deg  -> later s
    //   bufB: N      dinv -> later mfloat
    //   h1:   N*128
    //   g:    N*128  (GCN out; first N*64 reused as GAT acc after GEMM2)
    //   h2:   N*64
    //   es:   N
    //   ed:   N
    //   mkey: N (unsigned)
    float* ws   = (float*)d_ws;
    float* deg  = ws;                       // N
    float* dinv = ws + (size_t)N;           // N
    float* h1   = ws + (size_t)2 * N;       // N*HID
    float* g    = h1 + (size_t)N * HID;     // N*HID
    float* h2   = g + (size_t)N * HID;      // N*OUT_H
    float* es   = h2 + (size_t)N * OUT_H;   // N
    float* ed   = es + (size_t)N;           // N
    unsigned* mkey = (unsigned*)(ed + (size_t)N); // N
    float* sden   = deg;   // alias
    float* mfloat = dinv;  // alias
    float* acc    = g;     // alias (g dead after GEMM2)

    // zero init (workspace is poisoned before every launch)
    hipMemsetAsync(deg, 0, (size_t)N * 4, stream);
    hipMemsetAsync(g, 0, (size_t)N * HID * 4, stream);
    hipMemsetAsync(mkey, 0, (size_t)N * 4, stream);

    // 1) degree + norm
    deg_kernel<<<(E + 255) / 256, 256, 0, stream>>>(coli, E, deg);
    dinv_kernel<<<(N + 255) / 256, 256, 0, stream>>>(deg, dinv, N);

    // 2) h1 = x @ W1   [N,165]@[165,128]
    {
        dim3 grid(HID / 128, (N + 63) / 64);
        gemm_kernel<64, 128, 16, 8, 4><<<grid, 256, 0, stream>>>(x, W1, h1, N, IN_DIM, HID);
    }

    // 3) GCN scatter + epilogue
    gcn_scatter<<<(E + 3) / 4, 256, 0, stream>>>(rowi, coli, E, h1, dinv, g);
    {
        size_t tot = (size_t)N * HID;
        gcn_finish<<<(unsigned)((tot + 255) / 256), 256, 0, stream>>>(h1, dinv, b1, g, N);
    }

    // 4) h2 = g @ Wg   [N,128]@[128,64]
    {
        dim3 grid(OUT_H / 64, (N + 63) / 64);
        gemm_kernel<64, 64, 32, 4, 4><<<grid, 256, 0, stream>>>(g, Wg, h2, N, HID, OUT_H);
    }

    // 5) attention coefficients
    attn_coef<<<(N + 3) / 4, 256, 0, stream>>>(h2, a_src, a_dst, es, ed, N);

    // 6) segment max over dst
    gat_max<<<(E + 255) / 256, 256, 0, stream>>>(rowi, coli, E, es, ed, mkey);

    // 7) self-loop init of m, s, acc
    gat_selfinit<<<(N + 3) / 4, 256, 0, stream>>>(h2, es, ed, mkey, mfloat, sden, acc, N);

    // 8) GAT edge scatter (numerator and denominator together)
    gat_scatter<<<(E + 3) / 4, 256, 0, stream>>>(rowi, coli, E, es, ed, mfloat, h2, sden, acc);

    // 9) epilogue: relu(acc/s + bg) @ Wfc + bfc
    gat_finish<<<(N + 3) / 4, 256, 0, stream>>>(acc, sden, bg, Wfc, bfc, out, N);
}

// Round 2
// 817.640 us; speedup vs baseline: 1.9539x; 1.9539x over previous
//
#include <hip/hip_runtime.h>
#include <math.h>

#define NSL 0.2f   // leaky relu negative slope
#define IN_DIM 165
#define HID 128
#define OUT_H 64
#define SCAN_B 512  // elements per scan block

// ---------- integer degree ----------
__global__ __launch_bounds__(256) void deg_kernel(const int* __restrict__ col, int E,
                                                  int* __restrict__ degi) {
    int e = blockIdx.x * 256 + threadIdx.x;
    if (e < E) atomicAdd(&degi[col[e]], 1);
}

// ---------- block-level inclusive scan (512 elems / block) ----------
__global__ __launch_bounds__(SCAN_B) void scan_block(const int* __restrict__ degi,
                                                     int* __restrict__ incl,
                                                     int* __restrict__ bsums, int n) {
    __shared__ int tmp[SCAN_B];
    int tid = threadIdx.x;
    int gid = blockIdx.x * SCAN_B + tid;
    int v = (gid < n) ? degi[gid] : 0;
    tmp[tid] = v;
    __syncthreads();
    for (int off = 1; off < SCAN_B; off <<= 1) {
        int t = (tid >= off) ? tmp[tid - off] : 0;
        __syncthreads();
        tmp[tid] += t;
        __syncthreads();
    }
    if (gid < n) incl[gid] = tmp[tid];
    if (tid == SCAN_B - 1) bsums[blockIdx.x] = tmp[tid];
}

// ---------- single-block exclusive scan of block sums (nb <= 256) ----------
__global__ __launch_bounds__(256) void scan_bsums(int* __restrict__ bsums, int nb) {
    __shared__ int tmp[256];
    int tid = threadIdx.x;
    int v = (tid < nb) ? bsums[tid] : 0;
    tmp[tid] = v;
    __syncthreads();
    for (int off = 1; off < 256; off <<= 1) {
        int t = (tid >= off) ? tmp[tid - off] : 0;
        __syncthreads();
        tmp[tid] += t;
        __syncthreads();
    }
    if (tid < nb) bsums[tid] = tmp[tid] - v;   // exclusive
}

// ---------- finalize: offsets[i] = exclusive scan; cursor copy; offsets[n]=E ----------
__global__ __launch_bounds__(256) void scan_finalize(const int* __restrict__ degi,
                                                     const int* __restrict__ bsums,
                                                     int* __restrict__ offsets,  // holds incl on entry
                                                     int* __restrict__ cursor,
                                                     int n, int E) {
    int gid = blockIdx.x * 256 + threadIdx.x;
    if (gid < n) {
        int excl = offsets[gid] - degi[gid] + bsums[gid >> 9];
        offsets[gid] = excl;
        cursor[gid] = excl;
    } else if (gid == n) {
        offsets[n] = E;
    }
}

// ---------- bucket fill: csr_src[pos] = row ----------
__global__ __launch_bounds__(256) void csr_fill(const int* __restrict__ rowi,
                                                const int* __restrict__ coli, int E,
                                                int* __restrict__ cursor,
                                                int* __restrict__ csr_src) {
    int e = blockIdx.x * 256 + threadIdx.x;
    if (e >= E) return;
    int p = atomicAdd(&cursor[coli[e]], 1);
    csr_src[p] = rowi[e];
}

// ---------- dinv ----------
__global__ __launch_bounds__(256) void dinv_kernel(const int* __restrict__ degi,
                                                   float* __restrict__ dinv, int n) {
    int i = blockIdx.x * 256 + threadIdx.x;
    if (i < n) dinv[i] = rsqrtf((float)degi[i] + 1.0f);   // +1 = self loop
}

// ---------- generic tiled fp32 GEMM: C[M,N] = A[M,K] @ B[K,N] ----------
template<int BM, int BN, int BK, int TM, int TN>
__global__ __launch_bounds__(256) void gemm_kernel(const float* __restrict__ A,
                                                   const float* __restrict__ B,
                                                   float* __restrict__ C,
                                                   int M, int K, int N) {
    __shared__ float As[BM][BK + 1];
    __shared__ float Bs[BK][BN];
    const int t = threadIdx.x;
    const int tx = t % (BN / TN);
    const int ty = t / (BN / TN);
    const int row0 = blockIdx.y * BM;
    const int col0 = blockIdx.x * BN;

    float acc[TM][TN];
#pragma unroll
    for (int r = 0; r < TM; r++)
#pragma unroll
        for (int c = 0; c < TN; c++) acc[r][c] = 0.f;

    for (int k0 = 0; k0 < K; k0 += BK) {
        for (int i = t; i < BM * BK; i += 256) {
            int r = i / BK, c = i % BK;
            int gr = row0 + r, gc = k0 + c;
            As[r][c] = (gr < M && gc < K) ? A[(size_t)gr * K + gc] : 0.f;
        }
        for (int i = t; i < BK * BN; i += 256) {
            int r = i / BN, c = i % BN;
            int gr = k0 + r;
            Bs[r][c] = (gr < K) ? B[(size_t)gr * N + col0 + c] : 0.f;
        }
        __syncthreads();
#pragma unroll
        for (int kk = 0; kk < BK; kk++) {
            float a[TM], b[TN];
#pragma unroll
            for (int r = 0; r < TM; r++) a[r] = As[ty * TM + r][kk];
#pragma unroll
            for (int c = 0; c < TN; c++) b[c] = Bs[kk][tx * TN + c];
#pragma unroll
            for (int r = 0; r < TM; r++)
#pragma unroll
                for (int c = 0; c < TN; c++) acc[r][c] += a[r] * b[c];
        }
        __syncthreads();
    }
#pragma unroll
    for (int r = 0; r < TM; r++) {
        int gr = row0 + ty * TM + r;
        if (gr < M) {
#pragma unroll
            for (int c = 0; c < TN; c++)
                C[(size_t)gr * N + col0 + tx * TN + c] = acc[r][c];
        }
    }
}

// ---------- GCN gather (wave per dst node) + self-loop + bias + relu ----------
__global__ __launch_bounds__(256) void gcn_gather(const int* __restrict__ offsets,
                                                  const int* __restrict__ csr_src,
                                                  const float* __restrict__ h1,
                                                  const float* __restrict__ dinv,
                                                  const float* __restrict__ b1,
                                                  float* __restrict__ g, int n) {
    int node = (blockIdx.x * 256 + threadIdx.x) >> 6;
    int lane = threadIdx.x & 63;
    if (node >= n) return;
    int s0 = offsets[node], s1 = offsets[node + 1];
    float dc = dinv[node];
    float dd = dc * dc;
    float a0 = h1[(size_t)node * HID + lane] * dd;        // self loop
    float a1 = h1[(size_t)node * HID + 64 + lane] * dd;
    for (int k = s0; k < s1; k++) {
        int r = csr_src[k];
        float nrm = dinv[r] * dc;
        a0 += h1[(size_t)r * HID + lane] * nrm;
        a1 += h1[(size_t)r * HID + 64 + lane] * nrm;
    }
    g[(size_t)node * HID + lane]      = fmaxf(a0 + b1[lane], 0.f);
    g[(size_t)node * HID + 64 + lane] = fmaxf(a1 + b1[64 + lane], 0.f);
}

// ---------- per-node attention coefficients ----------
__global__ __launch_bounds__(256) void attn_coef(const float* __restrict__ h2,
                                                 const float* __restrict__ a_src,
                                                 const float* __restrict__ a_dst,
                                                 float* __restrict__ es,
                                                 float* __restrict__ ed, int n) {
    int i = blockIdx.x * 4 + (threadIdx.x >> 6);
    int lane = threadIdx.x & 63;
    if (i >= n) return;
    float h = h2[(size_t)i * OUT_H + lane];
    float vs = h * a_src[lane];
    float vd = h * a_dst[lane];
    for (int off = 32; off; off >>= 1) {
        vs += __shfl_down(vs, off);
        vd += __shfl_down(vd, off);
    }
    if (lane == 0) { es[i] = vs; ed[i] = vd; }
}

// ---------- fused GAT: online softmax gather + relu + FC (wave per dst node) ----------
__global__ __launch_bounds__(256) void gat_fused(const int* __restrict__ offsets,
                                                 const int* __restrict__ csr_src,
                                                 const float* __restrict__ h2,
                                                 const float* __restrict__ es,
                                                 const float* __restrict__ ed,
                                                 const float* __restrict__ bg,
                                                 const float* __restrict__ Wfc,
                                                 const float* __restrict__ bfc,
                                                 float* __restrict__ out, int n) {
    int node = (blockIdx.x * 256 + threadIdx.x) >> 6;
    int lane = threadIdx.x & 63;
    if (node >= n) return;
    int s0 = offsets[node], s1 = offsets[node + 1];
    float edc = ed[node];

    // self-loop init
    float eself = es[node] + edc;
    eself = eself > 0.f ? eself : NSL * eself;
    float m = eself;
    float s = 1.0f;
    float acc = h2[(size_t)node * OUT_H + lane];

    for (int k = s0; k < s1; k++) {
        int r = csr_src[k];
        float v = es[r] + edc;
        v = v > 0.f ? v : NSL * v;
        float mn = fmaxf(m, v);
        float sc = __expf(m - mn);
        float ex = __expf(v - mn);
        s = s * sc + ex;
        acc = acc * sc + ex * h2[(size_t)r * OUT_H + lane];
        m = mn;
    }

    float o = fmaxf(acc / s + bg[lane], 0.f);
    float p0 = o * Wfc[lane * 2 + 0];
    float p1 = o * Wfc[lane * 2 + 1];
    for (int off = 32; off; off >>= 1) {
        p0 += __shfl_down(p0, off);
        p1 += __shfl_down(p1, off);
    }
    if (lane == 0) {
        out[(size_t)node * 2 + 0] = p0 + bfc[0];
        out[(size_t)node * 2 + 1] = p1 + bfc[1];
    }
}

extern "C" void kernel_launch(void* const* d_in, const int* in_sizes, int n_in,
                              void* d_out, int out_size, void* d_ws, size_t ws_size,
                              hipStream_t stream) {
    const float* x     = (const float*)d_in[0];
    const int*   ei    = (const int*)d_in[1];
    const float* W1    = (const float*)d_in[2];
    const float* b1    = (const float*)d_in[3];
    const float* Wg    = (const float*)d_in[4];
    const float* a_src = (const float*)d_in[5];
    const float* a_dst = (const float*)d_in[6];
    const float* bg    = (const float*)d_in[7];
    const float* Wfc   = (const float*)d_in[8];
    const float* bfc   = (const float*)d_in[9];
    float* out = (float*)d_out;

    const int N = in_sizes[0] / IN_DIM;
    const int E = in_sizes[1] / 2;
    const int* rowi = ei;
    const int* coli = ei + E;

    // workspace layout (4-byte units), total ~278N + E + pad ≈ 111 MB:
    char* wsb = (char*)d_ws;
    int*   degi    = (int*)wsb;                         // N
    int*   offsets = degi + N;                          // N+8 (padded)
    float* dinv    = (float*)(offsets + N + 8);         // N
    float* es      = dinv + N;                          // N
    float* ed      = es + N;                            // N
    int*   cursor  = (int*)(ed + N);                    // N
    int*   bsums   = cursor + N;                        // 512
    int*   csr_src = bsums + 512;                       // E
    float* h1      = (float*)(csr_src + E);             // N*128
    float* g       = h1 + (size_t)N * HID;              // N*128
    float* h2      = h1;                                // alias: h1 dead after gcn_gather

    // zero init (workspace is poisoned before every launch)
    hipMemsetAsync(degi, 0, (size_t)N * 4, stream);

    const int nbScan = (N + SCAN_B - 1) / SCAN_B;

    // 1) CSR build: degree -> scan -> fill; plus dinv
    deg_kernel<<<(E + 255) / 256, 256, 0, stream>>>(coli, E, degi);
    scan_block<<<nbScan, SCAN_B, 0, stream>>>(degi, offsets, bsums, N);
    scan_bsums<<<1, 256, 0, stream>>>(bsums, nbScan);
    scan_finalize<<<(N + 256) / 256, 256, 0, stream>>>(degi, bsums, offsets, cursor, N, E);
    csr_fill<<<(E + 255) / 256, 256, 0, stream>>>(rowi, coli, E, cursor, csr_src);
    dinv_kernel<<<(N + 255) / 256, 256, 0, stream>>>(degi, dinv, N);

    // 2) h1 = x @ W1   [N,165]@[165,128]
    {
        dim3 grid(HID / 128, (N + 63) / 64);
        gemm_kernel<64, 128, 16, 8, 4><<<grid, 256, 0, stream>>>(x, W1, h1, N, IN_DIM, HID);
    }

    // 3) GCN gather (fused self-loop + bias + relu)
    gcn_gather<<<(N + 3) / 4, 256, 0, stream>>>(offsets, csr_src, h1, dinv, b1, g, N);

    // 4) h2 = g @ Wg   [N,128]@[128,64]   (h2 aliases h1 — h1 is dead now)
    {
        dim3 grid(OUT_H / 64, (N + 63) / 64);
        gemm_kernel<64, 64, 32, 4, 4><<<grid, 256, 0, stream>>>(g, Wg, h2, N, HID, OUT_H);
    }

    // 5) attention coefficients
    attn_coef<<<(N + 3) / 4, 256, 0, stream>>>(h2, a_src, a_dst, es, ed, N);

    // 6) fused GAT: online-softmax gather + relu + final FC
    gat_fused<<<(N + 3) / 4, 256, 0, stream>>>(offsets, csr_src, h2, es, ed, bg, Wfc, bfc, out, N);
}